// Round 3
// baseline (32386.420 us; speedup 1.0000x reference)
//
#include <hip/hip_runtime.h>

// CVRAE forward — weight-stationary XCD column partitioning.
// B=256, S=512, A=64, H=1024, Z=256. NWG=256 (1 WG/CU, 32 WGs/XCD).
//
// Each XCD owns a COLUMN slice of every phase's output; its weight slice
// (~2.4 MB) stays L2-resident forever (zero per-step weight refill; was
// 18 MB/XCD/step streamed from LLC). Activations cross XCDs via the LLC
// using agent-scope relaxed atomics (sc0 sc1: bypass L1+L2, read/write at
// the coherence point), so no cache invalidation of L2 is ever needed.
// Phase boundaries are relaxed-tree global barriers (no acq/rel -> the
// compiler emits no L2-invalidating cache ops) + buffer_inv sc0 (L1 only).
// Column alignment: XCD g owns enc/pri cols [g*256,..), gate cols
// j in [g*128,..) in BOTH P1 (gh producer) and P4 (gh consumer), z cols
// [g*32,..), pz cols [g*128,..) -> gh and hf stay XCD-local (normal L2 ops).

typedef float f32x4 __attribute__((ext_vector_type(4)));
typedef __bf16 bf16x8 __attribute__((ext_vector_type(8)));
typedef unsigned long long u64;
typedef u64 u64x2 __attribute__((ext_vector_type(2)));

#define BB 256
#define SS 512
#define HH 1024
#define ZZ 256
#define AA 64
#define NWG 256

__device__ __forceinline__ float softplus_(float x) {
    return (x > 15.f) ? x : log1pf(expf(x));
}
__device__ __forceinline__ float sigmoid_(float x) {
    return 1.f / (1.f + expf(-x));
}

// ---- agent-scope (LLC coherence point) data movement helpers ----
__device__ __forceinline__ u64 ld8a(const __bf16* p) {
    return __hip_atomic_load((const u64*)p, __ATOMIC_RELAXED, __HIP_MEMORY_SCOPE_AGENT);
}
__device__ __forceinline__ bf16x8 ld16a(const __bf16* p) {
    u64x2 t; t.x = ld8a(p); t.y = ld8a(p + 4);
    return __builtin_bit_cast(bf16x8, t);
}
__device__ __forceinline__ void st2a(__bf16* p, float v) {
    unsigned w = __builtin_bit_cast(unsigned short, (__bf16)v);
    asm volatile("global_store_short %0, %1, off sc0 sc1" :: "v"(p), "v"(w) : "memory");
}

// ---- relaxed-tree global barrier (no L2-invalidating acquire) ----
// Data visibility: cross-XCD data is written with sc0sc1 stores (at LLC once
// vmcnt drains; __syncthreads drains vmcnt) and read with sc0sc1 loads, so
// only execution ordering + L1 invalidate are needed here.
__device__ __forceinline__ void gbarR(unsigned* bar, unsigned p, int wg) {
    __syncthreads();
    if (threadIdx.x == 0) {
        unsigned s = p & 7u;
        unsigned exp = (p >> 3) + 1u;
        unsigned* leaf = bar + (s * 8 + (wg >> 5)) * 16;
        unsigned* root = bar + (64 + s) * 16;
        unsigned* flag = bar + (72 + s) * 16;
        unsigned old = __hip_atomic_fetch_add(leaf, 1u, __ATOMIC_RELAXED, __HIP_MEMORY_SCOPE_AGENT);
        if (old == 32u * exp - 1u) {
            unsigned old2 = __hip_atomic_fetch_add(root, 1u, __ATOMIC_RELAXED, __HIP_MEMORY_SCOPE_AGENT);
            if (old2 == 8u * exp - 1u)
                __hip_atomic_store(flag, exp, __ATOMIC_RELAXED, __HIP_MEMORY_SCOPE_AGENT);
        }
        while (__hip_atomic_load(flag, __ATOMIC_RELAXED, __HIP_MEMORY_SCOPE_AGENT) < exp)
            __builtin_amdgcn_s_sleep(2);
    }
    asm volatile("buffer_inv sc0" ::: "memory");
    __syncthreads();
}

// ---- per-XCD barrier (tail only) ----
__device__ __forceinline__ void xbar(unsigned* flags, int g, int rank, int ngrp,
                                     unsigned tok) {
    __syncthreads();
    if (threadIdx.x == 0)
        __hip_atomic_store(flags + g * 256 + rank, tok, __ATOMIC_RELAXED,
                           __HIP_MEMORY_SCOPE_AGENT);
    unsigned l = threadIdx.x & 63;
    unsigned* base = flags + g * 256;
    for (;;) {
        bool ok = true;
        for (int i = (int)l; i < ngrp; i += 64)
            ok &= (__hip_atomic_load(base + i, __ATOMIC_RELAXED,
                                     __HIP_MEMORY_SCOPE_AGENT) >= tok);
        if (__all(ok)) break;
        __builtin_amdgcn_s_sleep(2);
    }
    asm volatile("buffer_inv sc0" ::: "memory");
    __syncthreads();
}

// ---------------- wave GEMM helper (tail) ----------------
template<int MT, int NT>
__device__ __forceinline__ void wgemm(const __bf16* __restrict__ A, int lda, int mstride,
                                      const __bf16* __restrict__ B, int ldb, int nstride,
                                      int K, f32x4 (&acc)[MT][NT]) {
    int lane = threadIdx.x & 63;
    int rr = lane & 15;
    int ko = (lane >> 4) * 8;
    const __bf16* ap = A + rr * lda + ko;
    const __bf16* bp = B + rr * ldb + ko;
    #pragma unroll 2
    for (int k = 0; k < K; k += 32) {
        bf16x8 af[MT], bfr[NT];
        #pragma unroll
        for (int mt = 0; mt < MT; mt++) af[mt] = *(const bf16x8*)(ap + mt * mstride + k);
        #pragma unroll
        for (int nt = 0; nt < NT; nt++) bfr[nt] = *(const bf16x8*)(bp + nt * nstride + k);
        #pragma unroll
        for (int mt = 0; mt < MT; mt++)
            #pragma unroll
            for (int nt = 0; nt < NT; nt++)
                acc[mt][nt] = __builtin_amdgcn_mfma_f32_16x16x32_bf16(af[mt], bfr[nt], acc[mt][nt], 0, 0, 0);
    }
}

// ---------------- prep kernels ----------------

__global__ void k_zeroctl(unsigned* bar, unsigned* flags, unsigned* cnt, float* kldacc) {
    for (int i = threadIdx.x; i < 1280; i += 256) bar[i] = 0u;
    for (int i = threadIdx.x; i < 2048; i += 256) flags[i] = 0u;
    if (threadIdx.x < 8) cnt[threadIdx.x] = 0u;
    if (threadIdx.x == 0) *kldacc = 0.f;
}

__global__ void k_pack(const float* __restrict__ src, int src_ld, int col_off,
                       __bf16* __restrict__ dst, int cols, int total) {
    int i = blockIdx.x * 256 + threadIdx.x;
    if (i >= total) return;
    int r = i / cols, c = i - r * cols;
    dst[i] = (__bf16)src[r * src_ld + col_off + c];
}

__global__ void k_copyf(const float* __restrict__ s, float* __restrict__ d, int n) {
    int i = blockIdx.x * 256 + threadIdx.x;
    if (i < n) d[i] = s[i];
}

__global__ void k_px(const float* __restrict__ phi_x_w, const float* __restrict__ phi_x_b,
                     float* __restrict__ px) {
    int i = blockIdx.x * 256 + threadIdx.x;  // 64*1024
    int a = i >> 10, hh = i & 1023;
    px[i] = fmaxf(phi_x_w[hh * AA + a] + phi_x_b[hh], 0.f);
}

__global__ __launch_bounds__(256) void k_tables(const float* __restrict__ enc_w1,
                                                const float* __restrict__ wih,
                                                const float* __restrict__ px,
                                                float* __restrict__ encpx,
                                                float* __restrict__ gipx) {
    __shared__ float spx[64][65];
    int tid = threadIdx.x;
    int cg = blockIdx.x * 4 + (tid >> 6);
    int a = tid & 63;
    const float* wrow = (cg < 1024) ? (enc_w1 + cg * 2048) : (wih + (cg - 1024) * 2048);
    float sum = 0.f;
    for (int k0 = 0; k0 < 1024; k0 += 64) {
        __syncthreads();
        for (int e = tid; e < 4096; e += 256)
            spx[e >> 6][e & 63] = px[((e >> 6) << 10) + k0 + (e & 63)];
        __syncthreads();
        #pragma unroll 8
        for (int kk = 0; kk < 64; kk++) sum += wrow[k0 + kk] * spx[a][kk];
    }
    if (cg < 1024) encpx[a * 1024 + cg] = sum;
    else gipx[a * 3072 + (cg - 1024)] = sum;
}

// ---------------- persistent kernel ----------------

struct PArgs {
    const int* x; const float* eps;
    const __bf16 *WA, *W2, *WPZ, *WIH, *WHH, *WDEC, *WACT;
    const float *encpx, *gipx;
    const float *eb1, *pb1, *eb2, *pb2, *pzb, *decb, *actb, *bih, *bhh;
    float *hf0, *hf1; __bf16 *hb0, *hb1;
    __bf16 *hidcat, *zbuf, *pzbuf, *tailhid, *decbuf;
    float *gh; float *kldacc; unsigned *bar, *flags, *cnt;
    float* out;
};

__global__ __launch_bounds__(256, 1) void k_persist(PArgs a) {
    int wg = blockIdx.x;
    int tid = threadIdx.x;
    int v = tid >> 6;                // wave in WG
    int lane = tid & 63;
    int rr = lane & 15;              // fragment row
    int ko = (lane >> 4) * 8;        // fragment k-offset
    int col = lane & 15, rq = (lane >> 4) * 4;
    float kl = 0.f;
    float* hf[2] = {a.hf0, a.hf1};
    __bf16* hb[2] = {a.hb0, a.hb1};

    __shared__ __align__(16) __bf16 Alds[16][1032];  // staged A m-tile (padded)
    __shared__ float lds2[4][2][256];                // P2 K-split partials
    __shared__ int sh_g, sh_rank, sh_ngrp;
    __shared__ float sh_kl[4];

    // ---- XCD registration ----
    if (tid == 0) {
        unsigned xcc = __builtin_amdgcn_s_getreg((31 << 11) | (0 << 6) | 20) & 7u;
        sh_g = (int)xcc;
        sh_rank = (int)atomicAdd(a.cnt + xcc, 1u);
    }
    __syncthreads();
    int g = sh_g, rank = sh_rank;
    gbarR(a.bar, 0, wg);
    if (tid == 0)
        sh_ngrp = (int)__hip_atomic_load(a.cnt + g, __ATOMIC_RELAXED,
                                         __HIP_MEMORY_SCOPE_AGENT);
    __syncthreads();
    int ngrp = sh_ngrp;
    int base_m = g * 32;             // tail still batch-partitioned

    unsigned gp = 1;                 // global barrier phase counter

    for (int t = 0; t < SS; t++) {
        int cur = t & 1, nxt = cur ^ 1;

        // ==== P1: XCD g owns 40 n-tiles: enc/pri cols [g*256,g*256+256) and
        //     gate cols {gate*1024 + g*128 + 0..127}. All 256 batch rows.
        //     jobs: 16 m-tiles x 8 groups of 5 n-tiles; WG shares one m-tile,
        //     A (h) staged to LDS via agent loads. ====
        for (int r0 = rank; r0 < 32; r0 += ngrp) {
            int mt = r0 & 15;
            __syncthreads();
            {
                const __bf16* src = hb[cur] + (size_t)(mt * 16) * HH + tid * 4;
                u64 tmp[16];
                #pragma unroll
                for (int e2 = 0; e2 < 16; e2++) tmp[e2] = ld8a(src + (size_t)e2 * HH);
                #pragma unroll
                for (int e2 = 0; e2 < 16; e2++)
                    *(u64*)((char*)(&Alds[e2][0]) + tid * 8) = tmp[e2];
            }
            __syncthreads();
            int ntg = (r0 >> 4) + 2 * v;           // 0..7
            const __bf16* bp[5]; int qv[5];
            #pragma unroll
            for (int j = 0; j < 5; j++) {
                int q = ntg * 5 + j; qv[j] = q;
                const __bf16* b;
                if (q < 16) b = a.WA + (size_t)(g * 256 + q * 16 + rr) * HH;
                else {
                    int qq = q - 16;
                    b = a.WHH + (size_t)((qq >> 3) * 1024 + g * 128 + (qq & 7) * 16 + rr) * HH;
                }
                bp[j] = b + ko;
            }
            f32x4 acc[5] = {};
            const __bf16* arow = &Alds[rr][ko];
            #pragma unroll 4
            for (int k = 0; k < HH; k += 32) {
                bf16x8 af = *(const bf16x8*)(arow + k);
                #pragma unroll
                for (int j = 0; j < 5; j++)
                    acc[j] = __builtin_amdgcn_mfma_f32_16x16x32_bf16(
                        af, *(const bf16x8*)(bp[j] + k), acc[j], 0, 0, 0);
            }
            int xb[4];
            #pragma unroll
            for (int i = 0; i < 4; i++) xb[i] = a.x[(mt * 16 + rq + i) * SS + t];
            #pragma unroll
            for (int j = 0; j < 5; j++) {
                int q = qv[j];
                if (q < 16) {
                    int c = g * 256 + q * 16 + col;
                    if (c < 1024) {
                        float bias = a.eb1[c];
                        #pragma unroll
                        for (int i = 0; i < 4; i++) {
                            int m = mt * 16 + rq + i;
                            float val = acc[j][i] + bias + a.encpx[xb[i] * 1024 + c];
                            st2a(&a.hidcat[(size_t)m * 2048 + c], fmaxf(val, 0.f));
                        }
                    } else {
                        float bias = a.pb1[c - 1024];
                        #pragma unroll
                        for (int i = 0; i < 4; i++) {
                            int m = mt * 16 + rq + i;
                            st2a(&a.hidcat[(size_t)m * 2048 + c], fmaxf(acc[j][i] + bias, 0.f));
                        }
                    }
                } else {
                    int qq = q - 16;
                    int gc = (qq >> 3) * 1024 + g * 128 + (qq & 7) * 16 + col;
                    #pragma unroll
                    for (int i = 0; i < 4; i++)
                        a.gh[(size_t)(mt * 16 + rq + i) * 3072 + gc] = acc[j][i];  // local
                }
            }
        }
        gbarR(a.bar, gp++, wg);

        // ==== P2: XCD g owns z-cols [g*32,(g+1)*32), enc+pri, all rows.
        //     32 items (16 m-tiles x 2 z-tiles), K split over 4 waves. ====
        for (int r = rank; r < 32; r += ngrp) {
            int mtl = r >> 1;                       // global m-tile
            int zsl = g * 2 + (r & 1);              // global z-tile
            const __bf16* ae_p = a.hidcat + (size_t)(mtl * 16 + rr) * 2048 + v * 256 + ko;
            const __bf16* ap_p = ae_p + 1024;
            const __bf16* be_p = a.W2 + (size_t)(zsl * 16 + rr) * HH + v * 256 + ko;
            const __bf16* bp_p = a.W2 + (size_t)(256 + zsl * 16 + rr) * HH + v * 256 + ko;
            bf16x8 aef[8], apf[8];
            #pragma unroll
            for (int k8 = 0; k8 < 8; k8++) {
                aef[k8] = ld16a(ae_p + k8 * 32);
                apf[k8] = ld16a(ap_p + k8 * 32);
            }
            f32x4 ae = {0.f,0.f,0.f,0.f}, av = {0.f,0.f,0.f,0.f};
            #pragma unroll
            for (int k8 = 0; k8 < 8; k8++) {
                ae = __builtin_amdgcn_mfma_f32_16x16x32_bf16(
                    aef[k8], *(const bf16x8*)(be_p + k8 * 32), ae, 0, 0, 0);
                av = __builtin_amdgcn_mfma_f32_16x16x32_bf16(
                    apf[k8], *(const bf16x8*)(bp_p + k8 * 32), av, 0, 0, 0);
            }
            #pragma unroll
            for (int i = 0; i < 4; i++) {
                int idx = (rq + i) * 16 + col;
                lds2[v][0][idx] = ae[i];
                lds2[v][1][idx] = av[i];
            }
            __syncthreads();
            {
                float e = lds2[0][0][tid] + lds2[1][0][tid] + lds2[2][0][tid] + lds2[3][0][tid];
                float pv = lds2[0][1][tid] + lds2[1][1][tid] + lds2[2][1][tid] + lds2[3][1][tid];
                int m = mtl * 16 + (tid >> 4);
                int z = zsl * 16 + (tid & 15);
                float enc = e + a.eb2[z];
                float pri = pv + a.pb2[z];
                float es = softplus_(enc), ps = softplus_(pri);
                float d = enc - pri;
                kl += 2.f * (logf(ps) - logf(es)) + (es * es + d * d) / (ps * ps) - 1.f;
                const float* epst = a.eps + (size_t)t * BB * ZZ;
                st2a(&a.zbuf[(size_t)m * ZZ + z], epst[m * ZZ + z] * es + enc);
            }
            __syncthreads();
        }
        gbarR(a.bar, gp++, wg);

        // ==== P3: XCD g owns pz-cols [g*128,(g+1)*128), all rows, K=256. ====
        for (int r0 = rank; r0 < 32; r0 += ngrp) {
            int mt = r0 & 15;
            int nt = (r0 >> 4) + 2 * v;             // 0..7 local
            const __bf16* apz = a.zbuf + (size_t)(mt * 16 + rr) * ZZ + ko;
            const __bf16* bpz = a.WPZ + (size_t)((g * 8 + nt) * 16 + rr) * ZZ + ko;
            bf16x8 azf[8];
            #pragma unroll
            for (int k8 = 0; k8 < 8; k8++) azf[k8] = ld16a(apz + k8 * 32);
            f32x4 acc = {0.f,0.f,0.f,0.f};
            #pragma unroll
            for (int k8 = 0; k8 < 8; k8++)
                acc = __builtin_amdgcn_mfma_f32_16x16x32_bf16(
                    azf[k8], *(const bf16x8*)(bpz + k8 * 32), acc, 0, 0, 0);
            int n = (g * 8 + nt) * 16 + col;
            float b = a.pzb[n];
            #pragma unroll
            for (int i = 0; i < 4; i++)
                st2a(&a.pzbuf[(size_t)(mt * 16 + rq + i) * HH + n], fmaxf(acc[i] + b, 0.f));
        }
        gbarR(a.bar, gp++, wg);

        // ==== P4: XCD g owns h-cols j in [g*128,(g+1)*128), all rows, 3 gates,
        //     K=1024. WG shares m-tile; pzbuf staged to LDS via agent loads. ====
        for (int r0 = rank; r0 < 32; r0 += ngrp) {
            int mt = r0 & 15;
            __syncthreads();
            {
                const __bf16* src = a.pzbuf + (size_t)(mt * 16) * HH + tid * 4;
                u64 tmp[16];
                #pragma unroll
                for (int e2 = 0; e2 < 16; e2++) tmp[e2] = ld8a(src + (size_t)e2 * HH);
                #pragma unroll
                for (int e2 = 0; e2 < 16; e2++)
                    *(u64*)((char*)(&Alds[e2][0]) + tid * 8) = tmp[e2];
            }
            __syncthreads();
            int jt = (r0 >> 4) + 2 * v;             // 0..7 local
            int jtg = g * 8 + jt;                   // global j-tile
            const __bf16* bp0 = a.WIH + (size_t)(jtg * 16 + rr) * HH + ko;
            const __bf16* bp1g = bp0 + (size_t)1024 * HH;
            const __bf16* bp2g = bp0 + (size_t)2048 * HH;
            f32x4 acc[3] = {};
            const __bf16* arow = &Alds[rr][ko];
            #pragma unroll 4
            for (int k = 0; k < HH; k += 32) {
                bf16x8 af = *(const bf16x8*)(arow + k);
                acc[0] = __builtin_amdgcn_mfma_f32_16x16x32_bf16(af, *(const bf16x8*)(bp0 + k), acc[0], 0, 0, 0);
                acc[1] = __builtin_amdgcn_mfma_f32_16x16x32_bf16(af, *(const bf16x8*)(bp1g + k), acc[1], 0, 0, 0);
                acc[2] = __builtin_amdgcn_mfma_f32_16x16x32_bf16(af, *(const bf16x8*)(bp2g + k), acc[2], 0, 0, 0);
            }
            int j = jtg * 16 + col;
            float br = a.bih[j], bz2 = a.bih[1024 + j], bn = a.bih[2048 + j];
            float cr = a.bhh[j], cz = a.bhh[1024 + j], cn = a.bhh[2048 + j];
            #pragma unroll
            for (int i = 0; i < 4; i++) {
                int m = mt * 16 + rq + i;
                int xb = a.x[m * SS + t];
                const float* gpp = a.gipx + (size_t)xb * 3072;
                const float* ghrow = a.gh + (size_t)m * 3072;       // local
                float gir = acc[0][i] + gpp[j] + br;
                float giz = acc[1][i] + gpp[1024 + j] + bz2;
                float gin = acc[2][i] + gpp[2048 + j] + bn;
                float ghr = ghrow[j] + cr;
                float ghz = ghrow[1024 + j] + cz;
                float ghn = ghrow[2048 + j] + cn;
                float rg = sigmoid_(gir + ghr);
                float zg = sigmoid_(giz + ghz);
                float nn = tanhf(gin + rg * ghn);
                float hv2 = (1.f - zg) * nn + zg * hf[cur][(size_t)m * HH + j];
                hf[nxt][(size_t)m * HH + j] = hv2;                  // local (same wave next step)
                st2a(&hb[nxt][(size_t)m * HH + j], hv2);            // cross (next P1)
            }
        }
        gbarR(a.bar, gp++, wg);
    }

    // ---- tail (final h in buffer 0; batch-partitioned, XCD-local) ----
    unsigned tok = 1;
    // T1: tailhid = relu(h @ pri_w1^T + pb1), K=1024
    for (int r = rank; r < 32; r += ngrp) {
        int mt = v >> 1, nt = r * 2 + (v & 1);
        f32x4 acc[1][1] = {};
        wgemm<1, 1>(hb[0] + (size_t)(base_m + mt * 16) * HH, HH, 0,
                    a.WA + (size_t)(1024 + nt * 16) * HH, HH, 0, HH, acc);
        int n = nt * 16 + col;
        float b = a.pb1[n];
        #pragma unroll
        for (int i = 0; i < 4; i++) {
            int m = base_m + mt * 16 + rq + i;
            a.tailhid[m * HH + n] = (__bf16)fmaxf(acc[0][0][i] + b, 0.f);
        }
    }
    xbar(a.flags, g, rank, ngrp, tok++);
    // T2: pri logits -> z sample (eps[S])
    if (v == 0) {
        for (int r = rank; r < 32; r += ngrp) {
            int mtl = r >> 4, zt = r & 15;
            f32x4 apv[1][1] = {};
            wgemm<1, 1>(a.tailhid + (size_t)(base_m + mtl * 16) * HH, HH, 0,
                        a.W2 + (size_t)(256 + zt * 16) * HH, HH, 0, HH, apv);
            int z = zt * 16 + col;
            float bp = a.pb2[z];
            const float* epst = a.eps + (size_t)SS * BB * ZZ;
            #pragma unroll
            for (int i = 0; i < 4; i++) {
                int m = base_m + mtl * 16 + rq + i;
                float pri = apv[0][0][i] + bp;
                float ps = softplus_(pri);
                a.zbuf[m * ZZ + z] = (__bf16)(epst[m * ZZ + z] * ps + pri);
            }
        }
    }
    xbar(a.flags, g, rank, ngrp, tok++);
    // T3: pz, K=256
    for (int r = rank; r < 32; r += ngrp) {
        int mt = v >> 1, nt = r * 2 + (v & 1);
        f32x4 acc[1][1] = {};
        wgemm<1, 1>(a.zbuf + (size_t)(base_m + mt * 16) * ZZ, ZZ, 0,
                    a.WPZ + (size_t)(nt * 16) * ZZ, ZZ, 0, ZZ, acc);
        int n = nt * 16 + col;
        float b = a.pzb[n];
        #pragma unroll
        for (int i = 0; i < 4; i++) {
            int m = base_m + mt * 16 + rq + i;
            a.pzbuf[m * HH + n] = (__bf16)fmaxf(acc[0][0][i] + b, 0.f);
        }
    }
    xbar(a.flags, g, rank, ngrp, tok++);
    // T4: dec = relu([pz|h] @ dec_w^T + b), K=2048 in two halves
    for (int r = rank; r < 32; r += ngrp) {
        int mt = v >> 1, nt = r * 2 + (v & 1);
        f32x4 acc[1][1] = {};
        wgemm<1, 1>(a.pzbuf + (size_t)(base_m + mt * 16) * HH, HH, 0,
                    a.WDEC + (size_t)(nt * 16) * 2048, 2048, 0, HH, acc);
        wgemm<1, 1>(hb[0] + (size_t)(base_m + mt * 16) * HH, HH, 0,
                    a.WDEC + (size_t)(nt * 16) * 2048 + 1024, 2048, 0, HH, acc);
        int n = nt * 16 + col;
        float b = a.decb[n];
        #pragma unroll
        for (int i = 0; i < 4; i++) {
            int m = base_m + mt * 16 + rq + i;
            a.decbuf[m * HH + n] = (__bf16)fmaxf(acc[0][0][i] + b, 0.f);
        }
    }
    xbar(a.flags, g, rank, ngrp, tok++);
    // T5: pred = dec @ act_w^T + act_b (only slices 0..7)
    if (v == 0) {
        for (int r = rank; r < 32; r += ngrp) {
            if (r >= 8) continue;
            int mt = r >> 2, nt = r & 3;
            f32x4 acc[1][1] = {};
            wgemm<1, 1>(a.decbuf + (size_t)(base_m + mt * 16) * HH, HH, 0,
                        a.WACT + (size_t)(nt * 16) * HH, HH, 0, HH, acc);
            int n = nt * 16 + col;
            float b = a.actb[n];
            #pragma unroll
            for (int i = 0; i < 4; i++) {
                int m = base_m + mt * 16 + rq + i;
                a.out[m * AA + n] = acc[0][0][i] + b;
            }
        }
    }

    // ---- kld reduce: wave -> WG -> device atomic ----
    {
        float s = kl;
        #pragma unroll
        for (int off = 1; off < 64; off <<= 1) s += __shfl_xor(s, off);
        if (lane == 0) sh_kl[v] = s;
        __syncthreads();
        if (tid == 0) {
            float ws = sh_kl[0] + sh_kl[1] + sh_kl[2] + sh_kl[3];
            atomicAdd(a.kldacc, ws);
        }
    }
    gbarR(a.bar, gp++, wg);
    if (wg == 0 && tid == 0) {
        float s = __hip_atomic_load(a.kldacc, __ATOMIC_ACQUIRE, __HIP_MEMORY_SCOPE_AGENT);
        a.out[BB * AA] = 0.5f * s;
    }
}

extern "C" void kernel_launch(void* const* d_in, const int* in_sizes, int n_in,
                              void* d_out, int out_size, void* d_ws, size_t ws_size,
                              hipStream_t stream) {
    const int*   x       = (const int*)d_in[0];
    const float* h0      = (const float*)d_in[1];
    const float* eps     = (const float*)d_in[2];
    const float* phi_x_w = (const float*)d_in[3];
    const float* phi_x_b = (const float*)d_in[4];
    const float* enc_w1  = (const float*)d_in[5];
    const float* enc_b1  = (const float*)d_in[6];
    const float* enc_w2  = (const float*)d_in[7];
    const float* enc_b2  = (const float*)d_in[8];
    const float* pri_w1  = (const float*)d_in[9];
    const float* pri_b1  = (const float*)d_in[10];
    const float* pri_w2  = (const float*)d_in[11];
    const float* pri_b2  = (const float*)d_in[12];
    const float* phi_z_w = (const float*)d_in[13];
    const float* phi_z_b = (const float*)d_in[14];
    const float* dec_w   = (const float*)d_in[15];
    const float* dec_b   = (const float*)d_in[16];
    const float* act_w   = (const float*)d_in[17];
    const float* act_b   = (const float*)d_in[18];
    const float* gru_wih = (const float*)d_in[19];
    const float* gru_whh = (const float*)d_in[20];
    const float* gru_bih = (const float*)d_in[21];
    const float* gru_bhh = (const float*)d_in[22];

    char* p = (char*)d_ws;
    auto alloc = [&](size_t bytes) { char* r = p; p += (bytes + 255) & ~(size_t)255; return r; };

    __bf16* WA    = (__bf16*)alloc(2048 * 1024 * 2);
    __bf16* W2    = (__bf16*)alloc(512 * 1024 * 2);
    __bf16* WPZ   = (__bf16*)alloc(1024 * 256 * 2);
    __bf16* WIH   = (__bf16*)alloc(3072 * 1024 * 2);
    __bf16* WHH   = (__bf16*)alloc(3072 * 1024 * 2);
    __bf16* WDEC  = (__bf16*)alloc(1024 * 2048 * 2);
    __bf16* WACT  = (__bf16*)alloc(64 * 1024 * 2);
    float*  px    = (float*)alloc(64 * 1024 * 4);
    float*  encpx = (float*)alloc(64 * 1024 * 4);
    float*  gipx  = (float*)alloc(64 * 3072 * 4);
    float*  hf0   = (float*)alloc(BB * HH * 4);
    float*  hf1   = (float*)alloc(BB * HH * 4);
    __bf16* hb0   = (__bf16*)alloc(BB * HH * 2);
    __bf16* hb1   = (__bf16*)alloc(BB * HH * 2);
    __bf16* hidcat = (__bf16*)alloc(BB * 2048 * 2);
    __bf16* zbuf   = (__bf16*)alloc(BB * ZZ * 2);
    __bf16* pzbuf  = (__bf16*)alloc(BB * HH * 2);
    __bf16* tailhid = (__bf16*)alloc(BB * HH * 2);
    __bf16* decbuf  = (__bf16*)alloc(BB * HH * 2);
    float*  gh     = (float*)alloc(BB * 3072 * 4);
    unsigned* bar  = (unsigned*)alloc(1280 * 4);
    unsigned* flags = (unsigned*)alloc(2048 * 4);
    unsigned* cnt  = (unsigned*)alloc(64 * 4);
    float*  kldacc = (float*)alloc(256);

    auto pack = [&](const float* src, int src_ld, int off, __bf16* dst, int rows, int cols) {
        int total = rows * cols;
        k_pack<<<(total + 255) / 256, 256, 0, stream>>>(src, src_ld, off, dst, cols, total);
    };

    k_zeroctl<<<1, 256, 0, stream>>>(bar, flags, cnt, kldacc);
    pack(enc_w1, 2048, 1024, WA, 1024, 1024);
    pack(pri_w1, 1024, 0, WA + 1024 * 1024, 1024, 1024);
    pack(enc_w2, 1024, 0, W2, 256, 1024);
    pack(pri_w2, 1024, 0, W2 + 256 * 1024, 256, 1024);
    pack(phi_z_w, 256, 0, WPZ, 1024, 256);
    pack(gru_wih, 2048, 1024, WIH, 3072, 1024);
    pack(gru_whh, 1024, 0, WHH, 3072, 1024);
    pack(dec_w, 2048, 0, WDEC, 1024, 2048);
    pack(act_w, 1024, 0, WACT, 64, 1024);
    pack(h0, 1024, 0, hb0, 256, 1024);
    k_copyf<<<(BB * HH + 255) / 256, 256, 0, stream>>>(h0, hf0, BB * HH);
    k_px<<<(64 * 1024) / 256, 256, 0, stream>>>(phi_x_w, phi_x_b, px);
    k_tables<<<1024, 256, 0, stream>>>(enc_w1, gru_wih, px, encpx, gipx);

    PArgs pa;
    pa.x = x; pa.eps = eps;
    pa.WA = WA; pa.W2 = W2; pa.WPZ = WPZ; pa.WIH = WIH; pa.WHH = WHH;
    pa.WDEC = WDEC; pa.WACT = WACT;
    pa.encpx = encpx; pa.gipx = gipx;
    pa.eb1 = enc_b1; pa.pb1 = pri_b1; pa.eb2 = enc_b2; pa.pb2 = pri_b2;
    pa.pzb = phi_z_b; pa.decb = dec_b; pa.actb = act_b;
    pa.bih = gru_bih; pa.bhh = gru_bhh;
    pa.hf0 = hf0; pa.hf1 = hf1; pa.hb0 = hb0; pa.hb1 = hb1;
    pa.hidcat = hidcat; pa.zbuf = zbuf; pa.pzbuf = pzbuf;
    pa.tailhid = tailhid; pa.decbuf = decbuf;
    pa.gh = gh; pa.kldacc = kldacc;
    pa.bar = bar; pa.flags = flags; pa.cnt = cnt;
    pa.out = (float*)d_out;

    k_persist<<<dim3(NWG), dim3(256), 0, stream>>>(pa);
}